// Round 15
// baseline (308.792 us; speedup 1.0000x reference)
//
#include <hip/hip_runtime.h>
#include <hip/hip_bf16.h>

#define NFEAT 96
#define DIM 64

// ---------------- fused: dual skinny GEMM (layer 1) + partitioned histogram ----------------
// Blocks [0, mmB): mm.  Blocks [mmB, ...): histogram, int4-vectorized edge loop
// (4 independent filter+atomic chains per iteration to cover L2/L3 latency).
template <int K>
__global__ __launch_bounds__(256) void k_mm_hist(const float* __restrict__ X,
                                                 const float* __restrict__ Wl,
                                                 const float* __restrict__ Wr,
                                                 const float* __restrict__ b,
                                                 __hip_bfloat16* __restrict__ A,
                                                 __hip_bfloat16* __restrict__ B, int N,
                                                 const int* __restrict__ tgt,
                                                 int* __restrict__ cnt, int E,
                                                 int part_size, int mmB) {
    constexpr int ROWS = 32;
    __shared__ float xs[ROWS * K];
    const int t = threadIdx.x;

    if ((int)blockIdx.x >= mmB) {
        // ---- histogram branch (int4 edge loop) ----
        const int part = blockIdx.x & 7;                   // mmB%8==0 keeps alignment
        const int hb = blockIdx.x - mmB;
        const int q = hb >> 3;
        const int nq = (gridDim.x - mmB) >> 3;
        const int step = nq * blockDim.x * 4;
        const int E4 = E & ~3;
        for (int i = (q * blockDim.x + t) * 4; i < E4; i += step) {
            const int4 tv = *reinterpret_cast<const int4*>(tgt + i);
            if (tv.x / part_size == part) atomicAdd(&cnt[tv.x], 1);
            if (tv.y / part_size == part) atomicAdd(&cnt[tv.y], 1);
            if (tv.z / part_size == part) atomicAdd(&cnt[tv.z], 1);
            if (tv.w / part_size == part) atomicAdd(&cnt[tv.w], 1);
        }
        if (q == 0 && t < (E - E4)) {
            const int tg = tgt[E4 + t];
            if (tg / part_size == part) atomicAdd(&cnt[tg], 1);
        }
        return;
    }

    // ---- mm branch ----
    const int lane = t & 63;
    const int w = t >> 6;
    const int r0 = blockIdx.x * ROWS;
    const int nvalid = min(ROWS, N - r0);

    if (nvalid > 0) {
        const float4* src = reinterpret_cast<const float4*>(X + (size_t)r0 * K);
        float4* dst = reinterpret_cast<float4*>(xs);
        const int nv4 = (nvalid * K) >> 2;
        for (int c = t; c < nv4; c += 256) dst[c] = src[c];
    }
    const float bias = b[lane];
    __syncthreads();
    if (nvalid <= 0) return;

    const int rw = w * 8;
    float accl[8], accr[8];
#pragma unroll
    for (int i = 0; i < 8; ++i) { accl[i] = 0.f; accr[i] = 0.f; }

    for (int k = 0; k < K; k += 4) {
        const float wl0 = Wl[(k + 0) * DIM + lane];
        const float wl1 = Wl[(k + 1) * DIM + lane];
        const float wl2 = Wl[(k + 2) * DIM + lane];
        const float wl3 = Wl[(k + 3) * DIM + lane];
        const float wr0 = Wr[(k + 0) * DIM + lane];
        const float wr1 = Wr[(k + 1) * DIM + lane];
        const float wr2 = Wr[(k + 2) * DIM + lane];
        const float wr3 = Wr[(k + 3) * DIM + lane];
#pragma unroll
        for (int i = 0; i < 8; ++i) {
            const float4 xv = *reinterpret_cast<const float4*>(&xs[(rw + i) * K + k]);
            accl[i] = fmaf(xv.x, wl0, accl[i]);
            accl[i] = fmaf(xv.y, wl1, accl[i]);
            accl[i] = fmaf(xv.z, wl2, accl[i]);
            accl[i] = fmaf(xv.w, wl3, accl[i]);
            accr[i] = fmaf(xv.x, wr0, accr[i]);
            accr[i] = fmaf(xv.y, wr1, accr[i]);
            accr[i] = fmaf(xv.z, wr2, accr[i]);
            accr[i] = fmaf(xv.w, wr3, accr[i]);
        }
    }
#pragma unroll
    for (int i = 0; i < 8; ++i) {
        const int r = r0 + rw + i;
        if (r < N) {
            A[(size_t)r * DIM + lane] = __float2bfloat16(accl[i]);
            B[(size_t)r * DIM + lane] = __float2bfloat16(accr[i] + bias);
        }
    }
}

// ---- 3-phase scan ----

__global__ void k_scan1(const int* __restrict__ cnt, int* __restrict__ bsum, int N) {
    __shared__ int ws[4];
    const int t = threadIdx.x;
    const int lane = t & 63, w = t >> 6;
    const int base = blockIdx.x * 1024 + t * 4;
    int s = 0;
    if (base + 3 < N) {
        int4 v = *reinterpret_cast<const int4*>(cnt + base);
        s = v.x + v.y + v.z + v.w;
    } else {
        for (int i = 0; i < 4; ++i)
            if (base + i < N) s += cnt[base + i];
    }
    for (int off = 32; off; off >>= 1) s += __shfl_down(s, off, 64);
    if (lane == 0) ws[w] = s;
    __syncthreads();
    if (t == 0) bsum[blockIdx.x] = ws[0] + ws[1] + ws[2] + ws[3];
}

__global__ void k_scan2(const int* __restrict__ bsum, int* __restrict__ boff,
                        int* __restrict__ rowstart, int nb, int N) {
    const int lane = threadIdx.x;  // 64 threads = 1 wave
    int carry = 0;
    for (int b0 = 0; b0 < nb; b0 += 64) {
        int i = b0 + lane;
        int orig = (i < nb) ? bsum[i] : 0;
        int v = orig;
        for (int off = 1; off < 64; off <<= 1) {
            int u = __shfl_up(v, off, 64);
            if (lane >= off) v += u;
        }
        if (i < nb) boff[i] = carry + v - orig;
        carry += __shfl(v, 63, 64);
    }
    if (lane == 0) rowstart[N] = carry;
}

__global__ void k_scan3(const int* __restrict__ cnt, const int* __restrict__ boff,
                        int* __restrict__ rowstart, int* __restrict__ wpos, int N) {
    __shared__ int wsum[4];
    const int t = threadIdx.x;
    const int lane = t & 63, w = t >> 6;
    const int base = blockIdx.x * 1024 + t * 4;
    int4 v = make_int4(0, 0, 0, 0);
    if (base + 3 < N) {
        v = *reinterpret_cast<const int4*>(cnt + base);
    } else {
        int* p = &v.x;
        for (int i = 0; i < 4; ++i)
            if (base + i < N) p[i] = cnt[base + i];
    }
    const int s = v.x + v.y + v.z + v.w;
    int inc = s;
    for (int off = 1; off < 64; off <<= 1) {
        int u = __shfl_up(inc, off, 64);
        if (lane >= off) inc += u;
    }
    if (lane == 63) wsum[w] = inc;
    __syncthreads();
    int woff = 0;
    for (int i = 0; i < w; ++i) woff += wsum[i];
    int r = boff[blockIdx.x] + woff + inc - s;
    if (base + 0 < N) { rowstart[base + 0] = r; wpos[base + 0] = r; } r += v.x;
    if (base + 1 < N) { rowstart[base + 1] = r; wpos[base + 1] = r; } r += v.y;
    if (base + 2 < N) { rowstart[base + 2] = r; wpos[base + 2] = r; } r += v.z;
    if (base + 3 < N) { rowstart[base + 3] = r; wpos[base + 3] = r; }
}

// Partitioned scatter, int4-vectorized (4 independent filter+atomic+store chains).
__global__ void k_scatter(const int* __restrict__ src, const int* __restrict__ tgt,
                          int* __restrict__ wpos, int* __restrict__ csr_src, int E,
                          int part_size) {
    const int part = blockIdx.x & 7;
    const int q = blockIdx.x >> 3;
    const int nq = gridDim.x >> 3;
    const int step = nq * blockDim.x * 4;
    const int E4 = E & ~3;
    for (int i = (q * blockDim.x + threadIdx.x) * 4; i < E4; i += step) {
        const int4 tv = *reinterpret_cast<const int4*>(tgt + i);
        const int4 sv = *reinterpret_cast<const int4*>(src + i);
        if (tv.x / part_size == part) csr_src[atomicAdd(&wpos[tv.x], 1)] = sv.x;
        if (tv.y / part_size == part) csr_src[atomicAdd(&wpos[tv.y], 1)] = sv.y;
        if (tv.z / part_size == part) csr_src[atomicAdd(&wpos[tv.z], 1)] = sv.z;
        if (tv.w / part_size == part) csr_src[atomicAdd(&wpos[tv.w], 1)] = sv.w;
    }
    if (q == 0 && threadIdx.x < (E - E4)) {
        const int e = E4 + threadIdx.x;
        const int tg = tgt[e];
        if (tg / part_size == part) csr_src[atomicAdd(&wpos[tg], 1)] = src[e];
    }
}

// ---------------- fused: layer-1 aggregation + layer-2 dual GEMM ----------------
// Block owns 32 nodes: phase 1 aggregates H rows directly into LDS (H never
// hits memory), phase 2 runs the K=64 mm on them.
__global__ __launch_bounds__(256) void k_aggr_mm(const __hip_bfloat16* __restrict__ A1,
                                                 const __hip_bfloat16* __restrict__ B1,
                                                 const int* __restrict__ rowstart,
                                                 const int* __restrict__ csr_src,
                                                 const float* __restrict__ Wl,
                                                 const float* __restrict__ Wr,
                                                 const float* __restrict__ b,
                                                 __hip_bfloat16* __restrict__ A2,
                                                 __hip_bfloat16* __restrict__ B2, int N) {
    constexpr int K = DIM;
    __shared__ float xs[32 * K];
    const int t = threadIdx.x;
    const int lane = t & 63;
    const int w = t >> 6;
    const int r0 = blockIdx.x * 32;

    // phase 1: wave w aggregates nodes r0+w*8 .. +7 into xs (relu'd H rows)
    for (int kq = 0; kq < 8; ++kq) {
        const int n = r0 + w * 8 + kq;
        float v = 0.f;
        if (n < N) {
            const int e0 = rowstart[n];
            const int e1 = rowstart[n + 1];
            float s0 = 0.f, s1 = 0.f, s2 = 0.f, s3 = 0.f;
            int j = e0;
            for (; j + 3 < e1; j += 4) {
                const int c0 = csr_src[j];
                const int c1 = csr_src[j + 1];
                const int c2 = csr_src[j + 2];
                const int c3 = csr_src[j + 3];
                s0 += __bfloat162float(A1[(size_t)c0 * DIM + lane]);
                s1 += __bfloat162float(A1[(size_t)c1 * DIM + lane]);
                s2 += __bfloat162float(A1[(size_t)c2 * DIM + lane]);
                s3 += __bfloat162float(A1[(size_t)c3 * DIM + lane]);
            }
            for (; j < e1; ++j) s0 += __bfloat162float(A1[(size_t)csr_src[j] * DIM + lane]);
            v = ((s0 + s1) + (s2 + s3)) / fmaxf((float)(e1 - e0), 1.f) +
                __bfloat162float(B1[(size_t)n * DIM + lane]);
            v = fmaxf(v, 0.f);
        }
        xs[(w * 8 + kq) * K + lane] = v;
    }
    const float bias = b[lane];
    __syncthreads();

    // phase 2: K=64 dual mm on xs
    const int rw = w * 8;
    float accl[8], accr[8];
#pragma unroll
    for (int i = 0; i < 8; ++i) { accl[i] = 0.f; accr[i] = 0.f; }

    for (int k = 0; k < K; k += 4) {
        const float wl0 = Wl[(k + 0) * DIM + lane];
        const float wl1 = Wl[(k + 1) * DIM + lane];
        const float wl2 = Wl[(k + 2) * DIM + lane];
        const float wl3 = Wl[(k + 3) * DIM + lane];
        const float wr0 = Wr[(k + 0) * DIM + lane];
        const float wr1 = Wr[(k + 1) * DIM + lane];
        const float wr2 = Wr[(k + 2) * DIM + lane];
        const float wr3 = Wr[(k + 3) * DIM + lane];
#pragma unroll
        for (int i = 0; i < 8; ++i) {
            const float4 xv = *reinterpret_cast<const float4*>(&xs[(rw + i) * K + k]);
            accl[i] = fmaf(xv.x, wl0, accl[i]);
            accl[i] = fmaf(xv.y, wl1, accl[i]);
            accl[i] = fmaf(xv.z, wl2, accl[i]);
            accl[i] = fmaf(xv.w, wl3, accl[i]);
            accr[i] = fmaf(xv.x, wr0, accr[i]);
            accr[i] = fmaf(xv.y, wr1, accr[i]);
            accr[i] = fmaf(xv.z, wr2, accr[i]);
            accr[i] = fmaf(xv.w, wr3, accr[i]);
        }
    }
#pragma unroll
    for (int i = 0; i < 8; ++i) {
        const int r = r0 + rw + i;
        if (r < N) {
            A2[(size_t)r * DIM + lane] = __float2bfloat16(accl[i]);
            B2[(size_t)r * DIM + lane] = __float2bfloat16(accr[i] + bias);
        }
    }
}

// ---------------- final aggregation: out = sum(A[src])/max(deg,1) + B ----------------
__global__ void k_aggr_out(const __hip_bfloat16* __restrict__ A,
                           const __hip_bfloat16* __restrict__ Bm,
                           const int* __restrict__ rowstart, const int* __restrict__ csr_src,
                           float* __restrict__ out, int N) {
    const int lane = threadIdx.x & 63;
    const int wave = blockIdx.x * (blockDim.x >> 6) + (threadIdx.x >> 6);
    const int nwaves = gridDim.x * (blockDim.x >> 6);
    for (int n = wave; n < N; n += nwaves) {
        const int r0 = rowstart[n];
        const int r1 = rowstart[n + 1];
        float s0 = 0.f, s1 = 0.f, s2 = 0.f, s3 = 0.f;
        int j = r0;
        for (; j + 3 < r1; j += 4) {
            const int c0 = csr_src[j];
            const int c1 = csr_src[j + 1];
            const int c2 = csr_src[j + 2];
            const int c3 = csr_src[j + 3];
            s0 += __bfloat162float(A[(size_t)c0 * DIM + lane]);
            s1 += __bfloat162float(A[(size_t)c1 * DIM + lane]);
            s2 += __bfloat162float(A[(size_t)c2 * DIM + lane]);
            s3 += __bfloat162float(A[(size_t)c3 * DIM + lane]);
        }
        for (; j < r1; ++j) s0 += __bfloat162float(A[(size_t)csr_src[j] * DIM + lane]);
        const float c = (float)(r1 - r0);
        out[(size_t)n * DIM + lane] = ((s0 + s1) + (s2 + s3)) / fmaxf(c, 1.f) +
                                      __bfloat162float(Bm[(size_t)n * DIM + lane]);
    }
}

extern "C" void kernel_launch(void* const* d_in, const int* in_sizes, int n_in,
                              void* d_out, int out_size, void* d_ws, size_t ws_size,
                              hipStream_t stream) {
    const float* x   = (const float*)d_in[0];
    const int*   ei  = (const int*)d_in[1];
    const float* Wl1 = (const float*)d_in[2];
    const float* Wr1 = (const float*)d_in[3];
    const float* b1  = (const float*)d_in[4];
    const float* Wl2 = (const float*)d_in[5];
    const float* Wr2 = (const float*)d_in[6];
    const float* b2  = (const float*)d_in[7];
    float* out = (float*)d_out;

    const int N = in_sizes[0] / NFEAT;
    const int E = in_sizes[1] / 2;
    const int* src = ei;
    const int* tgt = ei + E;

    char* ws = (char*)d_ws;
    size_t off = 0;
    auto alloc = [&](size_t bytes) -> void* {
        void* p = ws + off;
        off = (off + bytes + 255) & ~(size_t)255;
        return p;
    };
    const int nb = (N + 1023) / 1024;
    int*   cnt      = (int*)alloc((size_t)N * 4);
    int*   rowstart = (int*)alloc((size_t)(N + 1) * 4);
    int*   wpos     = (int*)alloc((size_t)N * 4);
    int*   bsum     = (int*)alloc((size_t)nb * 4);
    int*   boff     = (int*)alloc((size_t)nb * 4);
    int*   csr      = (int*)alloc((size_t)E * 4);
    __hip_bfloat16* A = (__hip_bfloat16*)alloc((size_t)N * DIM * 2);
    __hip_bfloat16* B = (__hip_bfloat16*)alloc((size_t)N * DIM * 2);
    __hip_bfloat16* A2 = (__hip_bfloat16*)alloc((size_t)N * DIM * 2);
    __hip_bfloat16* B2 = (__hip_bfloat16*)alloc((size_t)N * DIM * 2);

    hipMemsetAsync(cnt, 0, (size_t)N * 4, stream);

    const int part_size = (N + 7) / 8;
    const int mm_blocks = (N + 31) / 32;
    const int mmB = (mm_blocks + 7) & ~7;  // x8: keep hist bid&7 XCD-aligned
    const int histB = 2048;

    // fused: layer-1 mm (bf16 A,B) + partitioned int4 histogram
    k_mm_hist<NFEAT><<<mmB + histB, 256, 0, stream>>>(x, Wl1, Wr1, b1, A, B, N,
                                                      tgt, cnt, E, part_size, mmB);
    k_scan1<<<nb, 256, 0, stream>>>(cnt, bsum, N);
    k_scan2<<<1, 64, 0, stream>>>(bsum, boff, rowstart, nb, N);
    k_scan3<<<nb, 256, 0, stream>>>(cnt, boff, rowstart, wpos, N);
    k_scatter<<<2048, 256, 0, stream>>>(src, tgt, wpos, csr, E, part_size);

    // fused: layer-1 aggregation (H in LDS only) + layer-2 mm
    k_aggr_mm<<<mm_blocks, 256, 0, stream>>>(A, B, rowstart, csr,
                                             Wl2, Wr2, b2, A2, B2, N);

    // final aggregation -> out (fp32)
    k_aggr_out<<<2048, 256, 0, stream>>>(A2, B2, rowstart, csr, out, N);
}

// Round 16
// 264.569 us; speedup vs baseline: 1.1672x; 1.1672x over previous
//
#include <hip/hip_runtime.h>
#include <hip/hip_bf16.h>

#define NFEAT 96
#define DIM 64

// ---------------- fused: dual skinny GEMM (layer 1) + partitioned histogram ----------------
// Blocks [0, mmB): mm.  Blocks [mmB, ...): histogram, int4-vectorized edge loop
// (4 independent filter+atomic chains per iteration to cover L2/L3 latency).
template <int K>
__global__ __launch_bounds__(256) void k_mm_hist(const float* __restrict__ X,
                                                 const float* __restrict__ Wl,
                                                 const float* __restrict__ Wr,
                                                 const float* __restrict__ b,
                                                 __hip_bfloat16* __restrict__ A,
                                                 __hip_bfloat16* __restrict__ B, int N,
                                                 const int* __restrict__ tgt,
                                                 int* __restrict__ cnt, int E,
                                                 int part_size, int mmB) {
    constexpr int ROWS = 32;
    __shared__ float xs[ROWS * K];
    const int t = threadIdx.x;

    if ((int)blockIdx.x >= mmB) {
        // ---- histogram branch (int4 edge loop) ----
        const int part = blockIdx.x & 7;                   // mmB%8==0 keeps alignment
        const int hb = blockIdx.x - mmB;
        const int q = hb >> 3;
        const int nq = (gridDim.x - mmB) >> 3;
        const int step = nq * blockDim.x * 4;
        const int E4 = E & ~3;
        for (int i = (q * blockDim.x + t) * 4; i < E4; i += step) {
            const int4 tv = *reinterpret_cast<const int4*>(tgt + i);
            if (tv.x / part_size == part) atomicAdd(&cnt[tv.x], 1);
            if (tv.y / part_size == part) atomicAdd(&cnt[tv.y], 1);
            if (tv.z / part_size == part) atomicAdd(&cnt[tv.z], 1);
            if (tv.w / part_size == part) atomicAdd(&cnt[tv.w], 1);
        }
        if (q == 0 && t < (E - E4)) {
            const int tg = tgt[E4 + t];
            if (tg / part_size == part) atomicAdd(&cnt[tg], 1);
        }
        return;
    }

    // ---- mm branch ----
    const int lane = t & 63;
    const int w = t >> 6;
    const int r0 = blockIdx.x * ROWS;
    const int nvalid = min(ROWS, N - r0);

    if (nvalid > 0) {
        const float4* src = reinterpret_cast<const float4*>(X + (size_t)r0 * K);
        float4* dst = reinterpret_cast<float4*>(xs);
        const int nv4 = (nvalid * K) >> 2;
        for (int c = t; c < nv4; c += 256) dst[c] = src[c];
    }
    const float bias = b[lane];
    __syncthreads();
    if (nvalid <= 0) return;

    const int rw = w * 8;
    float accl[8], accr[8];
#pragma unroll
    for (int i = 0; i < 8; ++i) { accl[i] = 0.f; accr[i] = 0.f; }

    for (int k = 0; k < K; k += 4) {
        const float wl0 = Wl[(k + 0) * DIM + lane];
        const float wl1 = Wl[(k + 1) * DIM + lane];
        const float wl2 = Wl[(k + 2) * DIM + lane];
        const float wl3 = Wl[(k + 3) * DIM + lane];
        const float wr0 = Wr[(k + 0) * DIM + lane];
        const float wr1 = Wr[(k + 1) * DIM + lane];
        const float wr2 = Wr[(k + 2) * DIM + lane];
        const float wr3 = Wr[(k + 3) * DIM + lane];
#pragma unroll
        for (int i = 0; i < 8; ++i) {
            const float4 xv = *reinterpret_cast<const float4*>(&xs[(rw + i) * K + k]);
            accl[i] = fmaf(xv.x, wl0, accl[i]);
            accl[i] = fmaf(xv.y, wl1, accl[i]);
            accl[i] = fmaf(xv.z, wl2, accl[i]);
            accl[i] = fmaf(xv.w, wl3, accl[i]);
            accr[i] = fmaf(xv.x, wr0, accr[i]);
            accr[i] = fmaf(xv.y, wr1, accr[i]);
            accr[i] = fmaf(xv.z, wr2, accr[i]);
            accr[i] = fmaf(xv.w, wr3, accr[i]);
        }
    }
#pragma unroll
    for (int i = 0; i < 8; ++i) {
        const int r = r0 + rw + i;
        if (r < N) {
            A[(size_t)r * DIM + lane] = __float2bfloat16(accl[i]);
            B[(size_t)r * DIM + lane] = __float2bfloat16(accr[i] + bias);
        }
    }
}

// plain dual GEMM (layer 2): H fp32 in, A2/B2 bf16 out
template <int K>
__global__ __launch_bounds__(256) void k_mm(const float* __restrict__ X,
                                            const float* __restrict__ Wl,
                                            const float* __restrict__ Wr,
                                            const float* __restrict__ b,
                                            __hip_bfloat16* __restrict__ A,
                                            __hip_bfloat16* __restrict__ B, int N) {
    constexpr int ROWS = 32;
    __shared__ float xs[ROWS * K];
    const int t = threadIdx.x;
    const int lane = t & 63;
    const int w = t >> 6;
    const int r0 = blockIdx.x * ROWS;
    const int nvalid = min(ROWS, N - r0);

    {
        const float4* src = reinterpret_cast<const float4*>(X + (size_t)r0 * K);
        float4* dst = reinterpret_cast<float4*>(xs);
        const int nv4 = (nvalid * K) >> 2;
        for (int c = t; c < nv4; c += 256) dst[c] = src[c];
    }
    const float bias = b[lane];
    __syncthreads();

    const int rw = w * 8;
    float accl[8], accr[8];
#pragma unroll
    for (int i = 0; i < 8; ++i) { accl[i] = 0.f; accr[i] = 0.f; }

    for (int k = 0; k < K; k += 4) {
        const float wl0 = Wl[(k + 0) * DIM + lane];
        const float wl1 = Wl[(k + 1) * DIM + lane];
        const float wl2 = Wl[(k + 2) * DIM + lane];
        const float wl3 = Wl[(k + 3) * DIM + lane];
        const float wr0 = Wr[(k + 0) * DIM + lane];
        const float wr1 = Wr[(k + 1) * DIM + lane];
        const float wr2 = Wr[(k + 2) * DIM + lane];
        const float wr3 = Wr[(k + 3) * DIM + lane];
#pragma unroll
        for (int i = 0; i < 8; ++i) {
            const float4 xv = *reinterpret_cast<const float4*>(&xs[(rw + i) * K + k]);
            accl[i] = fmaf(xv.x, wl0, accl[i]);
            accl[i] = fmaf(xv.y, wl1, accl[i]);
            accl[i] = fmaf(xv.z, wl2, accl[i]);
            accl[i] = fmaf(xv.w, wl3, accl[i]);
            accr[i] = fmaf(xv.x, wr0, accr[i]);
            accr[i] = fmaf(xv.y, wr1, accr[i]);
            accr[i] = fmaf(xv.z, wr2, accr[i]);
            accr[i] = fmaf(xv.w, wr3, accr[i]);
        }
    }
#pragma unroll
    for (int i = 0; i < 8; ++i) {
        const int r = r0 + rw + i;
        if (r < N) {
            A[(size_t)r * DIM + lane] = __float2bfloat16(accl[i]);
            B[(size_t)r * DIM + lane] = __float2bfloat16(accr[i] + bias);
        }
    }
}

// ---- 3-phase scan ----

__global__ void k_scan1(const int* __restrict__ cnt, int* __restrict__ bsum, int N) {
    __shared__ int ws[4];
    const int t = threadIdx.x;
    const int lane = t & 63, w = t >> 6;
    const int base = blockIdx.x * 1024 + t * 4;
    int s = 0;
    if (base + 3 < N) {
        int4 v = *reinterpret_cast<const int4*>(cnt + base);
        s = v.x + v.y + v.z + v.w;
    } else {
        for (int i = 0; i < 4; ++i)
            if (base + i < N) s += cnt[base + i];
    }
    for (int off = 32; off; off >>= 1) s += __shfl_down(s, off, 64);
    if (lane == 0) ws[w] = s;
    __syncthreads();
    if (t == 0) bsum[blockIdx.x] = ws[0] + ws[1] + ws[2] + ws[3];
}

__global__ void k_scan2(const int* __restrict__ bsum, int* __restrict__ boff,
                        int* __restrict__ rowstart, int nb, int N) {
    const int lane = threadIdx.x;  // 64 threads = 1 wave
    int carry = 0;
    for (int b0 = 0; b0 < nb; b0 += 64) {
        int i = b0 + lane;
        int orig = (i < nb) ? bsum[i] : 0;
        int v = orig;
        for (int off = 1; off < 64; off <<= 1) {
            int u = __shfl_up(v, off, 64);
            if (lane >= off) v += u;
        }
        if (i < nb) boff[i] = carry + v - orig;
        carry += __shfl(v, 63, 64);
    }
    if (lane == 0) rowstart[N] = carry;
}

__global__ void k_scan3(const int* __restrict__ cnt, const int* __restrict__ boff,
                        int* __restrict__ rowstart, int* __restrict__ wpos, int N) {
    __shared__ int wsum[4];
    const int t = threadIdx.x;
    const int lane = t & 63, w = t >> 6;
    const int base = blockIdx.x * 1024 + t * 4;
    int4 v = make_int4(0, 0, 0, 0);
    if (base + 3 < N) {
        v = *reinterpret_cast<const int4*>(cnt + base);
    } else {
        int* p = &v.x;
        for (int i = 0; i < 4; ++i)
            if (base + i < N) p[i] = cnt[base + i];
    }
    const int s = v.x + v.y + v.z + v.w;
    int inc = s;
    for (int off = 1; off < 64; off <<= 1) {
        int u = __shfl_up(inc, off, 64);
        if (lane >= off) inc += u;
    }
    if (lane == 63) wsum[w] = inc;
    __syncthreads();
    int woff = 0;
    for (int i = 0; i < w; ++i) woff += wsum[i];
    int r = boff[blockIdx.x] + woff + inc - s;
    if (base + 0 < N) { rowstart[base + 0] = r; wpos[base + 0] = r; } r += v.x;
    if (base + 1 < N) { rowstart[base + 1] = r; wpos[base + 1] = r; } r += v.y;
    if (base + 2 < N) { rowstart[base + 2] = r; wpos[base + 2] = r; } r += v.z;
    if (base + 3 < N) { rowstart[base + 3] = r; wpos[base + 3] = r; }
}

// Partitioned scatter, int4-vectorized (4 independent filter+atomic+store chains).
__global__ void k_scatter(const int* __restrict__ src, const int* __restrict__ tgt,
                          int* __restrict__ wpos, int* __restrict__ csr_src, int E,
                          int part_size) {
    const int part = blockIdx.x & 7;
    const int q = blockIdx.x >> 3;
    const int nq = gridDim.x >> 3;
    const int step = nq * blockDim.x * 4;
    const int E4 = E & ~3;
    for (int i = (q * blockDim.x + threadIdx.x) * 4; i < E4; i += step) {
        const int4 tv = *reinterpret_cast<const int4*>(tgt + i);
        const int4 sv = *reinterpret_cast<const int4*>(src + i);
        if (tv.x / part_size == part) csr_src[atomicAdd(&wpos[tv.x], 1)] = sv.x;
        if (tv.y / part_size == part) csr_src[atomicAdd(&wpos[tv.y], 1)] = sv.y;
        if (tv.z / part_size == part) csr_src[atomicAdd(&wpos[tv.z], 1)] = sv.z;
        if (tv.w / part_size == part) csr_src[atomicAdd(&wpos[tv.w], 1)] = sv.w;
    }
    if (q == 0 && threadIdx.x < (E - E4)) {
        const int e = E4 + threadIdx.x;
        const int tg = tgt[e];
        if (tg / part_size == part) csr_src[atomicAdd(&wpos[tg], 1)] = src[e];
    }
}

// ---------------- per-node aggregation (layer 1): H = relu(sum(A[src])/deg + B) ----------------
template <bool RELU>
__global__ void k_aggr(const __hip_bfloat16* __restrict__ A,
                       const __hip_bfloat16* __restrict__ Bm,
                       const int* __restrict__ rowstart, const int* __restrict__ csr_src,
                       float* __restrict__ out, int N) {
    const int lane = threadIdx.x & 63;
    const int wave = blockIdx.x * (blockDim.x >> 6) + (threadIdx.x >> 6);
    const int nwaves = gridDim.x * (blockDim.x >> 6);
    for (int n = wave; n < N; n += nwaves) {
        const int r0 = rowstart[n];
        const int r1 = rowstart[n + 1];
        float s0 = 0.f, s1 = 0.f, s2 = 0.f, s3 = 0.f;
        int j = r0;
        for (; j + 3 < r1; j += 4) {
            const int c0 = csr_src[j];
            const int c1 = csr_src[j + 1];
            const int c2 = csr_src[j + 2];
            const int c3 = csr_src[j + 3];
            s0 += __bfloat162float(A[(size_t)c0 * DIM + lane]);
            s1 += __bfloat162float(A[(size_t)c1 * DIM + lane]);
            s2 += __bfloat162float(A[(size_t)c2 * DIM + lane]);
            s3 += __bfloat162float(A[(size_t)c3 * DIM + lane]);
        }
        for (; j < r1; ++j) s0 += __bfloat162float(A[(size_t)csr_src[j] * DIM + lane]);
        const float c = (float)(r1 - r0);
        float v = ((s0 + s1) + (s2 + s3)) / fmaxf(c, 1.f) +
                  __bfloat162float(Bm[(size_t)n * DIM + lane]);
        if (RELU) v = fmaxf(v, 0.f);
        out[(size_t)n * DIM + lane] = v;
    }
}

extern "C" void kernel_launch(void* const* d_in, const int* in_sizes, int n_in,
                              void* d_out, int out_size, void* d_ws, size_t ws_size,
                              hipStream_t stream) {
    const float* x   = (const float*)d_in[0];
    const int*   ei  = (const int*)d_in[1];
    const float* Wl1 = (const float*)d_in[2];
    const float* Wr1 = (const float*)d_in[3];
    const float* b1  = (const float*)d_in[4];
    const float* Wl2 = (const float*)d_in[5];
    const float* Wr2 = (const float*)d_in[6];
    const float* b2  = (const float*)d_in[7];
    float* out = (float*)d_out;

    const int N = in_sizes[0] / NFEAT;
    const int E = in_sizes[1] / 2;
    const int* src = ei;
    const int* tgt = ei + E;

    char* ws = (char*)d_ws;
    size_t off = 0;
    auto alloc = [&](size_t bytes) -> void* {
        void* p = ws + off;
        off = (off + bytes + 255) & ~(size_t)255;
        return p;
    };
    const int nb = (N + 1023) / 1024;
    int*   cnt      = (int*)alloc((size_t)N * 4);
    int*   rowstart = (int*)alloc((size_t)(N + 1) * 4);
    int*   wpos     = (int*)alloc((size_t)N * 4);
    int*   bsum     = (int*)alloc((size_t)nb * 4);
    int*   boff     = (int*)alloc((size_t)nb * 4);
    int*   csr      = (int*)alloc((size_t)E * 4);
    __hip_bfloat16* A = (__hip_bfloat16*)alloc((size_t)N * DIM * 2);
    __hip_bfloat16* B = (__hip_bfloat16*)alloc((size_t)N * DIM * 2);
    float* H        = (float*)alloc((size_t)N * DIM * 4);

    hipMemsetAsync(cnt, 0, (size_t)N * 4, stream);

    const int part_size = (N + 7) / 8;
    const int mm_blocks = (N + 31) / 32;
    const int mmB = (mm_blocks + 7) & ~7;  // x8: keep hist bid&7 XCD-aligned
    const int histB = 2048;

    // fused: layer-1 mm (bf16 A,B) + partitioned int4 histogram
    k_mm_hist<NFEAT><<<mmB + histB, 256, 0, stream>>>(x, Wl1, Wr1, b1, A, B, N,
                                                      tgt, cnt, E, part_size, mmB);
    k_scan1<<<nb, 256, 0, stream>>>(cnt, bsum, N);
    k_scan2<<<1, 64, 0, stream>>>(bsum, boff, rowstart, nb, N);
    k_scan3<<<nb, 256, 0, stream>>>(cnt, boff, rowstart, wpos, N);
    k_scatter<<<2048, 256, 0, stream>>>(src, tgt, wpos, csr, E, part_size);

    // layer 1 aggregation: H = relu(aggr(A)/deg + B)   (2048 blocks = 8192 waves)
    k_aggr<true><<<2048, 256, 0, stream>>>(A, B, rowstart, csr, H, N);

    // layer 2: A = H@Wl2 (bf16), B = H@Wr2 + b2 (bf16); out = aggr(A)/deg + B
    k_mm<DIM><<<mm_blocks, 256, 0, stream>>>(H, Wl2, Wr2, b2, A, B, N);
    k_aggr<false><<<2048, 256, 0, stream>>>(A, B, rowstart, csr, out, N);
}